// Round 7
// baseline (113.853 us; speedup 1.0000x reference)
//
#include <hip/hip_runtime.h>
#include <math.h>

#define NB 4
#define CH 2048
#define TPB 256            // 4 independent waves/block — no barriers, no LDS
#define NBLK 512           // 2048 waves x 4 tokens = 8192 tokens; whole grid resident
#define TOK_PER_WAVE 4
#define SINK_ITERS 20
#define EPS 1e-5f

typedef float f32x4 __attribute__((ext_vector_type(4)));

__device__ __forceinline__ float bcast_first(float v) {
    return __uint_as_float(__builtin_amdgcn_readfirstlane(__float_as_uint(v)));
}
__device__ __forceinline__ float read_lane(float v, int l) {
    return __uint_as_float(__builtin_amdgcn_readlane(__float_as_uint(v), l));
}

// Wave-per-token design:
//  - Each wave holds a full token (4 branches x 2048 ch) in registers:
//    lane l, branch n, chunk k -> float4 index l + 64k of row n. Coalesced.
//  - RMS reduce = 7 shuffles (2-step 4-value fold + 4-step butterfly),
//    totals broadcast via readlane into SGPRs. Zero LDS, zero barriers.
//  - Lane-parallel 4x4 Sinkhorn once per wave (amortized over 4 tokens),
//    overlapped with the w-register load.
__global__ __launch_bounds__(TPB, 2) void mhc_wave(
    const float* __restrict__ x,
    const float* __restrict__ w,
    const float* __restrict__ H_pre,
    const float* __restrict__ H_post,
    const float* __restrict__ H_res,
    float* __restrict__ y)
{
    const int t = threadIdx.x;
    const int wave = t >> 6;
    const int lane = t & 63;
    const int gw = blockIdx.x * (TPB / 64) + wave;   // 0..2047
    const int b0 = gw * TOK_PER_WAVE;

    // rmsnorm weight in registers for this lane's 32 channels (8 chunks)
    const f32x4* w4 = (const f32x4*)w;
    f32x4 wv[8];
    #pragma unroll
    for (int k = 0; k < 8; ++k)
        wv[k] = w4[lane + 64 * k];

    // ---- Lane-parallel Sinkhorn (overlaps the w loads above) ----
    const int e = lane & 15;          // matrix entry; 4 copies per wave
    float v = expf(H_res[e]);         // M[e>>2][e&3]
    #pragma unroll 1
    for (int it = 0; it < SINK_ITERS; ++it) {
        float s = v + __shfl_xor(v, 1);
        s += __shfl_xor(s, 2);
        v *= __builtin_amdgcn_rcpf(s + EPS);
        s = v + __shfl_xor(v, 4);
        s += __shfl_xor(s, 8);
        v *= __builtin_amdgcn_rcpf(s + EPS);
    }
    const float H00 = read_lane(v, 0),  H01 = read_lane(v, 1),
                H02 = read_lane(v, 2),  H03 = read_lane(v, 3);
    const float H10 = read_lane(v, 4),  H11 = read_lane(v, 5),
                H12 = read_lane(v, 6),  H13 = read_lane(v, 7);
    const float H20 = read_lane(v, 8),  H21 = read_lane(v, 9),
                H22 = read_lane(v, 10), H23 = read_lane(v, 11);
    const float H30 = read_lane(v, 12), H31 = read_lane(v, 13),
                H32 = read_lane(v, 14), H33 = read_lane(v, 15);

    const float pre0 = bcast_first(1.0f / (1.0f + expf(-H_pre[0])));
    const float pre1 = bcast_first(1.0f / (1.0f + expf(-H_pre[1])));
    const float pre2 = bcast_first(1.0f / (1.0f + expf(-H_pre[2])));
    const float pre3 = bcast_first(1.0f / (1.0f + expf(-H_pre[3])));
    const float ps0  = bcast_first(1.0f / (1.0f + expf(-H_post[0])));
    const float ps1  = bcast_first(1.0f / (1.0f + expf(-H_post[1])));
    const float ps2  = bcast_first(1.0f / (1.0f + expf(-H_post[2])));
    const float ps3  = bcast_first(1.0f / (1.0f + expf(-H_post[3])));

    #pragma unroll 1
    for (int tok = 0; tok < TOK_PER_WAVE; ++tok) {
        const int b = b0 + tok;
        const f32x4* xb = (const f32x4*)x + (size_t)b * (NB * CH / 4) + lane;

        // Whole token into registers (32 x f32x4 = 128 VGPR), read-once nt loads
        f32x4 xr[NB][8];
        #pragma unroll
        for (int n = 0; n < NB; ++n)
            #pragma unroll
            for (int k = 0; k < 8; ++k)
                xr[n][k] = __builtin_nontemporal_load(xb + n * (CH / 4) + k * 64);

        // Per-branch sum of squares over this lane's 32 channels
        float ss[NB] = {0.f, 0.f, 0.f, 0.f};
        #pragma unroll
        for (int n = 0; n < NB; ++n) {
            #pragma unroll
            for (int k = 0; k < 8; ++k) {
                f32x4 c = xr[n][k];
                ss[n] += c.x * c.x + c.y * c.y + c.z * c.z + c.w * c.w;
            }
        }

        // 4-value wave reduce in 7 shuffles:
        // fold pairs (xor 1), fold quads (xor 2) -> lane l holds branch (l&3)
        // partial over its 4-lane group; butterfly xor 4,8,16,32 -> totals.
        float x01 = (lane & 1) ? ss[1] : ss[0];
        float y01 = (lane & 1) ? ss[0] : ss[1];
        x01 += __shfl_xor(y01, 1);
        float x23 = (lane & 1) ? ss[3] : ss[2];
        float y23 = (lane & 1) ? ss[2] : ss[3];
        x23 += __shfl_xor(y23, 1);
        float z  = (lane & 2) ? x23 : x01;
        float zz = (lane & 2) ? x01 : x23;
        z += __shfl_xor(zz, 2);
        z += __shfl_xor(z, 4);
        z += __shfl_xor(z, 8);
        z += __shfl_xor(z, 16);
        z += __shfl_xor(z, 32);

        const float t0 = read_lane(z, 0);
        const float t1 = read_lane(z, 1);
        const float t2 = read_lane(z, 2);
        const float t3 = read_lane(z, 3);

        const float a0 = pre0 * rsqrtf(t0 * (1.0f / CH) + EPS);
        const float a1 = pre1 * rsqrtf(t1 * (1.0f / CH) + EPS);
        const float a2 = pre2 * rsqrtf(t2 * (1.0f / CH) + EPS);
        const float a3 = pre3 * rsqrtf(t3 * (1.0f / CH) + EPS);

        // Outputs chunk-by-chunk, straight from registers; write-once nt stores
        f32x4* yb = (f32x4*)y + (size_t)b * (NB * CH / 4) + lane;
        #pragma unroll
        for (int k = 0; k < 8; ++k) {
            const f32x4 c0 = xr[0][k], c1 = xr[1][k], c2 = xr[2][k], c3 = xr[3][k];
            const f32x4 wu = wv[k] * (a0 * c0 + a1 * c1 + a2 * c2 + a3 * c3);
            f32x4 o;
            o = H00 * c0 + H01 * c1 + H02 * c2 + H03 * c3 + ps0 * wu;
            __builtin_nontemporal_store(o, yb + 0 * (CH / 4) + k * 64);
            o = H10 * c0 + H11 * c1 + H12 * c2 + H13 * c3 + ps1 * wu;
            __builtin_nontemporal_store(o, yb + 1 * (CH / 4) + k * 64);
            o = H20 * c0 + H21 * c1 + H22 * c2 + H23 * c3 + ps2 * wu;
            __builtin_nontemporal_store(o, yb + 2 * (CH / 4) + k * 64);
            o = H30 * c0 + H31 * c1 + H32 * c2 + H33 * c3 + ps3 * wu;
            __builtin_nontemporal_store(o, yb + 3 * (CH / 4) + k * 64);
        }
    }
}

extern "C" void kernel_launch(void* const* d_in, const int* in_sizes, int n_in,
                              void* d_out, int out_size, void* d_ws, size_t ws_size,
                              hipStream_t stream) {
    const float* x      = (const float*)d_in[0];   // [B, N, C]
    const float* wgt    = (const float*)d_in[1];   // [C]
    const float* h_pre  = (const float*)d_in[2];   // [N]
    const float* h_post = (const float*)d_in[3];   // [N]
    const float* h_res  = (const float*)d_in[4];   // [N, N]
    float* y = (float*)d_out;                      // [B, N, C]

    mhc_wave<<<NBLK, TPB, 0, stream>>>(x, wgt, h_pre, h_post, h_res, y);
}

// Round 8
// 102.010 us; speedup vs baseline: 1.1161x; 1.1161x over previous
//
#include <hip/hip_runtime.h>
#include <math.h>

#define B_TOK 8192
#define NB 4
#define CH 2048
#define TPB 512            // 8 waves/block
#define NBLK 1024          // 8 tokens per block
#define TOK_PER_BLK 8
#define SINK_ITERS 20
#define EPS 1e-5f

typedef float f32x4 __attribute__((ext_vector_type(4)));

__device__ __forceinline__ float bcast_first(float v) {
    return __uint_as_float(__builtin_amdgcn_readfirstlane(__float_as_uint(v)));
}
__device__ __forceinline__ float read_lane(float v, int l) {
    return __uint_as_float(__builtin_amdgcn_readlane(__float_as_uint(v), l));
}

// R6 structure (102.4us) with a cheap reduce: 7-shuffle fold + 1 LDS write +
// 1 conflict-free LDS read + 3 shuffles + 4 readlane. DS ops/thread/token
// 33 -> 12; everything else unchanged (single-lever A/B vs R6).
__global__ __launch_bounds__(TPB) void mhc_fused(
    const float* __restrict__ x,
    const float* __restrict__ w,
    const float* __restrict__ H_pre,
    const float* __restrict__ H_post,
    const float* __restrict__ H_res,
    float* __restrict__ y)
{
    const int t = threadIdx.x;
    const int wave = t >> 6;
    const int lane = t & 63;
    const int b0 = blockIdx.x * TOK_PER_BLK;

    __shared__ float red[2][32];   // [phase][wave*4 + branch]

    // ---- Issue first loads BEFORE sinkhorn math (latency overlap) ----
    f32x4 xA0, xA1, xA2, xA3, xB0, xB1, xB2, xB3;
    auto xload = [&](int b, f32x4& d0, f32x4& d1, f32x4& d2, f32x4& d3) {
        const f32x4* p = (const f32x4*)x + (size_t)b * (NB * CH / 4) + t;
        d0 = __builtin_nontemporal_load(p);
        d1 = __builtin_nontemporal_load(p + (CH / 4));
        d2 = __builtin_nontemporal_load(p + 2 * (CH / 4));
        d3 = __builtin_nontemporal_load(p + 3 * (CH / 4));
    };
    xload(b0 + 0, xA0, xA1, xA2, xA3);
    xload(b0 + 1, xB0, xB1, xB2, xB3);
    const f32x4 wv = ((const f32x4*)w)[t];

    // ---- Lane-parallel Sinkhorn (runs while the loads above are in flight) --
    const int e = lane & 15;
    float v = expf(H_res[e]);
    #pragma unroll 1
    for (int it = 0; it < SINK_ITERS; ++it) {
        float s = v + __shfl_xor(v, 1);
        s += __shfl_xor(s, 2);
        v *= __builtin_amdgcn_rcpf(s + EPS);
        s = v + __shfl_xor(v, 4);
        s += __shfl_xor(s, 8);
        v *= __builtin_amdgcn_rcpf(s + EPS);
    }
    const float H00 = read_lane(v, 0),  H01 = read_lane(v, 1),
                H02 = read_lane(v, 2),  H03 = read_lane(v, 3);
    const float H10 = read_lane(v, 4),  H11 = read_lane(v, 5),
                H12 = read_lane(v, 6),  H13 = read_lane(v, 7);
    const float H20 = read_lane(v, 8),  H21 = read_lane(v, 9),
                H22 = read_lane(v, 10), H23 = read_lane(v, 11);
    const float H30 = read_lane(v, 12), H31 = read_lane(v, 13),
                H32 = read_lane(v, 14), H33 = read_lane(v, 15);

    const float pre0 = bcast_first(1.0f / (1.0f + expf(-H_pre[0])));
    const float pre1 = bcast_first(1.0f / (1.0f + expf(-H_pre[1])));
    const float pre2 = bcast_first(1.0f / (1.0f + expf(-H_pre[2])));
    const float pre3 = bcast_first(1.0f / (1.0f + expf(-H_pre[3])));
    const float ps0  = bcast_first(1.0f / (1.0f + expf(-H_post[0])));
    const float ps1  = bcast_first(1.0f / (1.0f + expf(-H_post[1])));
    const float ps2  = bcast_first(1.0f / (1.0f + expf(-H_post[2])));
    const float ps3  = bcast_first(1.0f / (1.0f + expf(-H_post[3])));

    auto process = [&](int b, f32x4 x0, f32x4 x1, f32x4 x2, f32x4 x3, int ph) {
        float s0 = x0.x * x0.x + x0.y * x0.y + x0.z * x0.z + x0.w * x0.w;
        float s1 = x1.x * x1.x + x1.y * x1.y + x1.z * x1.z + x1.w * x1.w;
        float s2 = x2.x * x2.x + x2.y * x2.y + x2.z * x2.z + x2.w * x2.w;
        float s3 = x3.x * x3.x + x3.y * x3.y + x3.z * x3.z + x3.w * x3.w;

        // Fold 4 values -> 1 per lane (3 shuffles): lane l ends holding the
        // 4-lane-group partial of branch (l&3); then 4-step butterfly.
        float a01 = (lane & 1) ? s1 : s0;
        float b01 = (lane & 1) ? s0 : s1;
        a01 += __shfl_xor(b01, 1);
        float a23 = (lane & 1) ? s3 : s2;
        float b23 = (lane & 1) ? s2 : s3;
        a23 += __shfl_xor(b23, 1);
        float c = (lane & 2) ? a23 : a01;
        float d = (lane & 2) ? a01 : a23;
        c += __shfl_xor(d, 2);
        c += __shfl_xor(c, 4);
        c += __shfl_xor(c, 8);
        c += __shfl_xor(c, 16);
        c += __shfl_xor(c, 32);
        // lane l: wave-total for branch (l&3)
        if (lane < 4) red[ph][wave * 4 + lane] = c;

        // LDS-only barrier: do NOT drain vmcnt (prefetch loads stay in flight)
        __builtin_amdgcn_sched_barrier(0);
        asm volatile("s_waitcnt lgkmcnt(0)" ::: "memory");
        __builtin_amdgcn_s_barrier();
        __builtin_amdgcn_sched_barrier(0);

        // Cross-wave combine: word (lane&31) = [wave=(l>>2)][branch=(l&3)],
        // conflict-free read, then sum over waves with 3 shuffles.
        float vv = red[ph][lane & 31];
        vv += __shfl_xor(vv, 4);
        vv += __shfl_xor(vv, 8);
        vv += __shfl_xor(vv, 16);
        const float t0 = read_lane(vv, 0);
        const float t1 = read_lane(vv, 1);
        const float t2 = read_lane(vv, 2);
        const float t3 = read_lane(vv, 3);

        const float a0 = pre0 * rsqrtf(t0 * (1.0f / CH) + EPS);
        const float a1 = pre1 * rsqrtf(t1 * (1.0f / CH) + EPS);
        const float a2 = pre2 * rsqrtf(t2 * (1.0f / CH) + EPS);
        const float a3 = pre3 * rsqrtf(t3 * (1.0f / CH) + EPS);

        f32x4 wu;
        wu.x = wv.x * (a0 * x0.x + a1 * x1.x + a2 * x2.x + a3 * x3.x);
        wu.y = wv.y * (a0 * x0.y + a1 * x1.y + a2 * x2.y + a3 * x3.y);
        wu.z = wv.z * (a0 * x0.z + a1 * x1.z + a2 * x2.z + a3 * x3.z);
        wu.w = wv.w * (a0 * x0.w + a1 * x1.w + a2 * x2.w + a3 * x3.w);

        f32x4* yp = (f32x4*)y + (size_t)b * (NB * CH / 4) + t;
        f32x4 o;
        o.x = H00 * x0.x + H01 * x1.x + H02 * x2.x + H03 * x3.x + ps0 * wu.x;
        o.y = H00 * x0.y + H01 * x1.y + H02 * x2.y + H03 * x3.y + ps0 * wu.y;
        o.z = H00 * x0.z + H01 * x1.z + H02 * x2.z + H03 * x3.z + ps0 * wu.z;
        o.w = H00 * x0.w + H01 * x1.w + H02 * x2.w + H03 * x3.w + ps0 * wu.w;
        __builtin_nontemporal_store(o, yp);
        o.x = H10 * x0.x + H11 * x1.x + H12 * x2.x + H13 * x3.x + ps1 * wu.x;
        o.y = H10 * x0.y + H11 * x1.y + H12 * x2.y + H13 * x3.y + ps1 * wu.y;
        o.z = H10 * x0.z + H11 * x1.z + H12 * x2.z + H13 * x3.z + ps1 * wu.z;
        o.w = H10 * x0.w + H11 * x1.w + H12 * x2.w + H13 * x3.w + ps1 * wu.w;
        __builtin_nontemporal_store(o, yp + (CH / 4));
        o.x = H20 * x0.x + H21 * x1.x + H22 * x2.x + H23 * x3.x + ps2 * wu.x;
        o.y = H20 * x0.y + H21 * x1.y + H22 * x2.y + H23 * x3.y + ps2 * wu.y;
        o.z = H20 * x0.z + H21 * x1.z + H22 * x2.z + H23 * x3.z + ps2 * wu.z;
        o.w = H20 * x0.w + H21 * x1.w + H22 * x2.w + H23 * x3.w + ps2 * wu.w;
        __builtin_nontemporal_store(o, yp + 2 * (CH / 4));
        o.x = H30 * x0.x + H31 * x1.x + H32 * x2.x + H33 * x3.x + ps3 * wu.x;
        o.y = H30 * x0.y + H31 * x1.y + H32 * x2.y + H33 * x3.y + ps3 * wu.y;
        o.z = H30 * x0.z + H31 * x1.z + H32 * x2.z + H33 * x3.z + ps3 * wu.z;
        o.w = H30 * x0.w + H31 * x1.w + H32 * x2.w + H33 * x3.w + ps3 * wu.w;
        __builtin_nontemporal_store(o, yp + 3 * (CH / 4));
    };

    // Software pipeline over 8 tokens: prefetch k+1 before processing k.
    process(b0 + 0, xA0, xA1, xA2, xA3, 0);
    xload(b0 + 2, xA0, xA1, xA2, xA3);
    process(b0 + 1, xB0, xB1, xB2, xB3, 1);
    xload(b0 + 3, xB0, xB1, xB2, xB3);
    process(b0 + 2, xA0, xA1, xA2, xA3, 0);
    xload(b0 + 4, xA0, xA1, xA2, xA3);
    process(b0 + 3, xB0, xB1, xB2, xB3, 1);
    xload(b0 + 5, xB0, xB1, xB2, xB3);
    process(b0 + 4, xA0, xA1, xA2, xA3, 0);
    xload(b0 + 6, xA0, xA1, xA2, xA3);
    process(b0 + 5, xB0, xB1, xB2, xB3, 1);
    xload(b0 + 7, xB0, xB1, xB2, xB3);
    process(b0 + 6, xA0, xA1, xA2, xA3, 0);
    process(b0 + 7, xB0, xB1, xB2, xB3, 1);
}

extern "C" void kernel_launch(void* const* d_in, const int* in_sizes, int n_in,
                              void* d_out, int out_size, void* d_ws, size_t ws_size,
                              hipStream_t stream) {
    const float* x      = (const float*)d_in[0];   // [B, N, C]
    const float* wgt    = (const float*)d_in[1];   // [C]
    const float* h_pre  = (const float*)d_in[2];   // [N]
    const float* h_post = (const float*)d_in[3];   // [N]
    const float* h_res  = (const float*)d_in[4];   // [N, N]
    float* y = (float*)d_out;                      // [B, N, C]

    mhc_fused<<<NBLK, TPB, 0, stream>>>(x, wgt, h_pre, h_post, h_res, y);
}